// Round 15
// baseline (234.269 us; speedup 1.0000x reference)
//
#include <hip/hip_runtime.h>
#include <hip/hip_bf16.h>

#define N_NODES 100000
#define N_EDGES 1600000
#define N_FEAT  16
#define HIDDEN  128
#define N_GRAPHS 512
#define CAP     64            // slots per node (mean deg 16, P(>63)~0)
#define NBKT    782           // ceil(100000/128) coarse buckets (dst>>7)
#define BN      128           // nodes per bucket
#define CAPB    2560          // edges per bucket cap (mean 2048, +11 sigma)
#define EPB     4000          // edges per k_part block (400 blocks)

typedef unsigned short ushort_t;
typedef short v8s __attribute__((ext_vector_type(8)));   // 8 bf16 (4 VGPRs)
typedef float v4f __attribute__((ext_vector_type(4)));   // MFMA accumulator

__device__ __forceinline__ ushort_t f2bf(float f) {
    __hip_bfloat16 b = __float2bfloat16(f);
    return *(ushort_t*)&b;
}
__device__ __forceinline__ float bf_lo(unsigned u) {
    union { unsigned i; float f; } c; c.i = u << 16; return c.f;
}
__device__ __forceinline__ float bf_hi(unsigned u) {
    union { unsigned i; float f; } c; c.i = u & 0xffff0000u; return c.f;
}

// ---------------- phase 1: coarse partition by dst>>7 (+ packB tail blocks) ----------------
// ebuf entry packed: v = src | (dst_local << 17)

__global__ __launch_bounds__(256) void k_part(const int* __restrict__ src,
                                              const int* __restrict__ dst,
                                              int* __restrict__ bcnt,
                                              int* __restrict__ ebuf,
                                              const float* __restrict__ W2,
                                              ushort_t* __restrict__ Bp) {
    int tid = threadIdx.x;

    if (blockIdx.x >= N_EDGES / EPB) {
        // packB: W2 -> bf16 MFMA B-fragment order
        int idx = (blockIdx.x - N_EDGES / EPB) * 256 + tid;   // 0..16383
        int j = idx & 7;
        int lane = (idx >> 3) & 63;
        int nt = (idx >> 9) & 7;
        int kt = idx >> 12;
        int k = kt * 32 + (lane >> 4) * 8 + j;
        int n = nt * 16 + (lane & 15);
        Bp[idx] = f2bf(W2[k * HIDDEN + n]);
        return;
    }

    __shared__ int h[NBKT];
    __shared__ int base[NBKT];
    __shared__ int r[NBKT];
    int e0 = blockIdx.x * EPB;

    for (int i = tid; i < NBKT; i += 256) { h[i] = 0; r[i] = 0; }
    __syncthreads();

    // EPB=4000: threads 0..159 handle 16 edges, the rest 15
    int nloc = (tid < EPB - 15 * 256) ? 16 : 15;
    int v[16], bb[16];
    #pragma unroll
    for (int k = 0; k < 16; ++k) {
        if (k < nloc) {
            int i = e0 + tid + k * 256;
            int s = src[i], d = dst[i];
            bb[k] = d >> 7;
            v[k] = s | ((d & 127) << 17);
            atomicAdd(&h[bb[k]], 1);
        }
    }
    __syncthreads();

    for (int i = tid; i < NBKT; i += 256)
        base[i] = atomicAdd(&bcnt[i], h[i]);
    __syncthreads();

    #pragma unroll
    for (int k = 0; k < 16; ++k) {
        if (k < nloc) {
            int b = bb[k];
            int pos = base[b] + atomicAdd(&r[b], 1);
            if (pos < CAPB) ebuf[b * CAPB + pos] = v[k];
        }
    }
}

// ---------------- phase 2: per-bucket LDS ranking + fused prescale ----------------

__global__ __launch_bounds__(256) void k_fill(const int* __restrict__ bcnt,
                                              const int* __restrict__ ebuf,
                                              const float* __restrict__ x,
                                              int* __restrict__ esrc64,
                                              int* __restrict__ cnt,
                                              float* __restrict__ dinv,
                                              ushort_t* __restrict__ xb,
                                              ushort_t* __restrict__ h1) {
    __shared__ int lcnt[BN];
    int tid = threadIdx.x;
    int b = blockIdx.x;
    int node0 = b << 7;

    if (tid < BN) lcnt[tid] = 0;
    __syncthreads();

    int nE = bcnt[b]; nE = nE > CAPB ? CAPB : nE;
    const int* eb = ebuf + b * CAPB;
    for (int i = tid; i < nE; i += 256) {
        int v = eb[i];
        int dl = v >> 17;
        int p = atomicAdd(&lcnt[dl], 1);
        if (p < CAP) esrc64[((node0 + dl) << 6) + p] = v & 0x1FFFF;
    }
    __syncthreads();

    if (tid < BN) {
        int node = node0 + tid;
        if (node < N_NODES) {
            int c = lcnt[tid];
            cnt[node] = c;
            dinv[node] = rsqrtf((float)c + 1.0f);
            int cc = c > CAP ? CAP : c;
            int pad = (cc + 7) & ~7;
            for (int p = cc; p < pad; ++p)
                esrc64[(node << 6) + p] = N_NODES;   // sentinel -> zero row
        }
    }

    for (int i = tid; i < BN * N_FEAT; i += 256) {
        int nl = i >> 4;
        int node = node0 + nl;
        if (node < N_NODES) {
            float di = rsqrtf((float)lcnt[nl] + 1.0f);
            xb[node * N_FEAT + (i & 15)] = f2bf(x[node * N_FEAT + (i & 15)] * di);
        }
    }

    if (b == 0) {
        if (tid < N_FEAT) xb[N_NODES * N_FEAT + tid] = 0;                 // xb sentinel row
        if (tid < HIDDEN) h1[(size_t)N_NODES * HIDDEN + tid] = 0;         // h1 sentinel row
    }
}

// ---------------- fused layer-1: wide-row gather (unroll 8) + LDS mm1 -> h1' ----------------

__global__ __launch_bounds__(256) void k_agg1f(const int* __restrict__ cnt,
                                               const int* __restrict__ esrc64,
                                               const float* __restrict__ dinv,
                                               const ushort_t* __restrict__ xb,
                                               const float* __restrict__ W1,
                                               const float* __restrict__ b1,
                                               ushort_t* __restrict__ h1) {
    __shared__ float sw[N_FEAT * HIDDEN];   // 8 KB
    __shared__ float sx[32][20];            // 16 feats padded to 20
    __shared__ float sdd[32];
    int tid = threadIdx.x;
    for (int i = tid; i < N_FEAT * HIDDEN; i += 256) sw[i] = W1[i];

    int wv = tid >> 6;
    int sub = (tid >> 3) & 7;    // node within wave
    int l8 = tid & 7;            // uint (2 feats) within row
    int nl = wv * 8 + sub;       // node local 0..31
    int node = blockIdx.x * 32 + nl;
    const unsigned* xr = (const unsigned*)xb;   // row = 8 uints

    int deg = cnt[node]; deg = deg > CAP ? CAP : deg;
    int deg8 = (deg + 7) & ~7;
    int base = node << 6;
    float dd = dinv[node];

    float a0 = 0.0f, a1 = 0.0f;
    for (int j = 0; j < deg8; j += 8) {
        int4 ia = *(const int4*)(esrc64 + base + j);
        int4 ib = *(const int4*)(esrc64 + base + j + 4);
        unsigned u0 = xr[(unsigned)ia.x * 8 + l8];
        unsigned u1 = xr[(unsigned)ia.y * 8 + l8];
        unsigned u2 = xr[(unsigned)ia.z * 8 + l8];
        unsigned u3 = xr[(unsigned)ia.w * 8 + l8];
        unsigned u4 = xr[(unsigned)ib.x * 8 + l8];
        unsigned u5 = xr[(unsigned)ib.y * 8 + l8];
        unsigned u6 = xr[(unsigned)ib.z * 8 + l8];
        unsigned u7 = xr[(unsigned)ib.w * 8 + l8];
        a0 += bf_lo(u0) + bf_lo(u1) + bf_lo(u2) + bf_lo(u3)
            + bf_lo(u4) + bf_lo(u5) + bf_lo(u6) + bf_lo(u7);
        a1 += bf_hi(u0) + bf_hi(u1) + bf_hi(u2) + bf_hi(u3)
            + bf_hi(u4) + bf_hi(u5) + bf_hi(u6) + bf_hi(u7);
    }
    unsigned su = xr[(unsigned)node * 8 + l8];
    a0 = (a0 + bf_lo(su)) * dd;
    a1 = (a1 + bf_hi(su)) * dd;

    sx[nl][2 * l8] = a0;
    sx[nl][2 * l8 + 1] = a1;
    if (l8 == 0) sdd[nl] = dd;
    __syncthreads();

    int f = tid & 127, half = tid >> 7;
    float bias = b1[f];
    float acc[16];
    #pragma unroll
    for (int n = 0; n < 16; ++n) acc[n] = bias;
    #pragma unroll
    for (int k4 = 0; k4 < 4; ++k4) {
        float w0 = sw[(k4 * 4 + 0) * HIDDEN + f];
        float w1 = sw[(k4 * 4 + 1) * HIDDEN + f];
        float w2 = sw[(k4 * 4 + 2) * HIDDEN + f];
        float w3 = sw[(k4 * 4 + 3) * HIDDEN + f];
        #pragma unroll
        for (int n = 0; n < 16; ++n) {
            float4 xv = *(const float4*)(&sx[half * 16 + n][k4 * 4]);
            acc[n] += xv.x * w0 + xv.y * w1 + xv.z * w2 + xv.w * w3;
        }
    }
    int n0 = blockIdx.x * 32 + half * 16;
    #pragma unroll
    for (int n = 0; n < 16; ++n)
        h1[(size_t)(n0 + n) * HIDDEN + f] =
            f2bf(sdd[half * 16 + n] * fmaxf(acc[n], 0.0f));
}

// ---------------- fused layer-2: gather -> LDS -> MFMA mm2 + head ----------------
// Block = 512 threads = 8 INDEPENDENT waves = 128 nodes; 33.8 KB LDS.
// No barrier: each wave writes and reads only its own 16-row LDS slice.

__global__ __launch_bounds__(512) void k_l2(const int* __restrict__ cnt,
                                            const int* __restrict__ esrc64,
                                            const float* __restrict__ dinv,
                                            const ushort_t* __restrict__ h1,
                                            const ushort_t* __restrict__ Bp,
                                            const float* __restrict__ b2,
                                            const float* __restrict__ Wl,
                                            float* __restrict__ snode) {
    __shared__ ushort_t sA[128 * 132];   // 33.8 KB
    int tid = threadIdx.x;
    int wv = tid >> 6, lane = tid & 63;
    int half = lane >> 5, l32 = lane & 31;
    int node0 = blockIdx.x * 128;
    const uint2* h = (const uint2*)h1;

    for (int p = 0; p < 8; ++p) {
        int nl = wv * 16 + p * 2 + half;
        int nodeIdx = node0 + nl;
        int node = nodeIdx < N_NODES ? nodeIdx : 0;   // clamp (only last block)
        int deg = cnt[node]; deg = deg > CAP ? CAP : deg;
        int deg8 = (deg + 7) & ~7;
        int base = node << 6;
        float dd = dinv[node];
        uint2 sv = h[node * 32 + l32];
        float a0 = bf_lo(sv.x), a1 = bf_hi(sv.x), a2 = bf_lo(sv.y), a3 = bf_hi(sv.y);

        for (int j = 0; j < deg8; j += 8) {
            int4 ia = *(const int4*)(esrc64 + base + j);
            int4 ib = *(const int4*)(esrc64 + base + j + 4);
            uint2 v0 = h[(unsigned)ia.x * 32 + l32];
            uint2 v1 = h[(unsigned)ia.y * 32 + l32];
            uint2 v2 = h[(unsigned)ia.z * 32 + l32];
            uint2 v3 = h[(unsigned)ia.w * 32 + l32];
            uint2 v4 = h[(unsigned)ib.x * 32 + l32];
            uint2 v5 = h[(unsigned)ib.y * 32 + l32];
            uint2 v6 = h[(unsigned)ib.z * 32 + l32];
            uint2 v7 = h[(unsigned)ib.w * 32 + l32];
            a0 += bf_lo(v0.x) + bf_lo(v1.x) + bf_lo(v2.x) + bf_lo(v3.x)
                + bf_lo(v4.x) + bf_lo(v5.x) + bf_lo(v6.x) + bf_lo(v7.x);
            a1 += bf_hi(v0.x) + bf_hi(v1.x) + bf_hi(v2.x) + bf_hi(v3.x)
                + bf_hi(v4.x) + bf_hi(v5.x) + bf_hi(v6.x) + bf_hi(v7.x);
            a2 += bf_lo(v0.y) + bf_lo(v1.y) + bf_lo(v2.y) + bf_lo(v3.y)
                + bf_lo(v4.y) + bf_lo(v5.y) + bf_lo(v6.y) + bf_lo(v7.y);
            a3 += bf_hi(v0.y) + bf_hi(v1.y) + bf_hi(v2.y) + bf_hi(v3.y)
                + bf_hi(v4.y) + bf_hi(v5.y) + bf_hi(v6.y) + bf_hi(v7.y);
        }
        ushort4 r;
        r.x = f2bf(a0 * dd); r.y = f2bf(a1 * dd);
        r.z = f2bf(a2 * dd); r.w = f2bf(a3 * dd);
        *(ushort4*)(&sA[nl * 132 + l32 * 4]) = r;
    }
    // no __syncthreads: wave reads only its own LDS rows (compiler waits lgkmcnt)

    // phase 2: MFMA. wave wv handles rows wv*16..+15 (the ones it wrote).
    int m = lane & 15, quad = lane >> 4;
    const ushort_t* arow = &sA[(wv * 16 + m) * 132];

    v4f acc[8];
    #pragma unroll
    for (int nt = 0; nt < 8; ++nt) acc[nt] = (v4f){0.f, 0.f, 0.f, 0.f};

    #pragma unroll
    for (int kt = 0; kt < 4; ++kt) {
        union { v8s v; ushort4 q[2]; } au;
        au.q[0] = *(const ushort4*)(arow + kt * 32 + quad * 8);
        au.q[1] = *(const ushort4*)(arow + kt * 32 + quad * 8 + 4);
        #pragma unroll
        for (int nt = 0; nt < 8; ++nt) {
            v8s b = *(const v8s*)(Bp + ((kt * 8 + nt) * 64 + lane) * 8);
            acc[nt] = __builtin_amdgcn_mfma_f32_16x16x32_bf16(au.v, b, acc[nt], 0, 0, 0);
        }
    }

    float part[4] = {0, 0, 0, 0};
    #pragma unroll
    for (int nt = 0; nt < 8; ++nt) {
        float bb = b2[nt * 16 + m];
        float wl = Wl[nt * 16 + m];
        #pragma unroll
        for (int reg = 0; reg < 4; ++reg)
            part[reg] += fmaxf(acc[nt][reg] + bb, 0.0f) * wl;
    }
    int node0b = node0 + wv * 16;
    #pragma unroll
    for (int reg = 0; reg < 4; ++reg) {
        float p = part[reg];
        p += __shfl_xor(p, 1, 64);
        p += __shfl_xor(p, 2, 64);
        p += __shfl_xor(p, 4, 64);
        p += __shfl_xor(p, 8, 64);
        int node = node0b + quad * 4 + reg;
        if (m == 0 && node < N_NODES) snode[node] = p;
    }
}

// ---------------- pooling: out[g] = mean(snode over graph g) + bl ----------------

__global__ __launch_bounds__(256) void k_pool(const float* __restrict__ snode,
                                              const int* __restrict__ batch,
                                              const float* __restrict__ bl,
                                              float* __restrict__ out) {
    int g = blockIdx.x;
    int tid = threadIdx.x;
    __shared__ float sred[4];

    int lo = 0, hi = N_NODES;
    while (lo < hi) { int mid = (lo + hi) >> 1; if (batch[mid] < g) lo = mid + 1; else hi = mid; }
    int start = lo;
    hi = N_NODES;
    while (lo < hi) { int mid = (lo + hi) >> 1; if (batch[mid] < g + 1) lo = mid + 1; else hi = mid; }
    int end = lo;

    float acc = 0.0f;
    for (int n = start + tid; n < end; n += 256) acc += snode[n];

    #pragma unroll
    for (int off = 32; off; off >>= 1) acc += __shfl_down(acc, off, 64);
    int wave = tid >> 6, lane = tid & 63;
    if (lane == 0) sred[wave] = acc;
    __syncthreads();
    if (tid == 0) {
        float s = sred[0] + sred[1] + sred[2] + sred[3];
        float cnt = (float)(end - start);
        out[g] = s / fmaxf(cnt, 1.0f) + bl[0];
    }
}

// ---------------- launch ----------------

extern "C" void kernel_launch(void* const* d_in, const int* in_sizes, int n_in,
                              void* d_out, int out_size, void* d_ws, size_t ws_size,
                              hipStream_t stream) {
    const float* x    = (const float*)d_in[0];
    const int*   src  = (const int*)d_in[1];
    const int*   dst  = src + N_EDGES;
    const int*   batch= (const int*)d_in[2];
    const float* W1   = (const float*)d_in[3];
    const float* b1   = (const float*)d_in[4];
    const float* W2   = (const float*)d_in[5];
    const float* b2   = (const float*)d_in[6];
    const float* Wl   = (const float*)d_in[7];
    const float* bl   = (const float*)d_in[8];
    float* out = (float*)d_out;

    // byte-offset workspace layout, 256 B aligned chunks
    char* w = (char*)d_ws;
    size_t off = 0;
    auto alloc = [&](size_t bytes) { char* p = w + off; off = (off + bytes + 255) & ~(size_t)255; return p; };

    ushort_t* h1   = (ushort_t*)alloc((size_t)(N_NODES + 1) * HIDDEN * 2);   // 25.6 MB (+sentinel)
    int*   ebuf    = (int*)alloc((size_t)NBKT * CAPB * 4);                    // 8.0 MB
    ushort_t* xb   = (ushort_t*)alloc((size_t)(N_NODES + 1) * N_FEAT * 2);   // 3.2 MB (+sentinel)
    float* dinv    = (float*)alloc(N_NODES * 4);
    float* snode   = (float*)alloc(N_NODES * 4);
    int*   cnt     = (int*)alloc(N_NODES * 4);
    int*   esrc64  = (int*)alloc((size_t)N_NODES * CAP * 4);                  // 25.6 MB
    ushort_t* Bp   = (ushort_t*)alloc(16384 * 2);                             // 32 KB
    int*   bcnt    = (int*)alloc(NBKT * 4);

    // build: memset bcnt, partition (+packB tail), per-bucket rank (+prescale+sentinels)
    hipMemsetAsync(bcnt, 0, NBKT * sizeof(int), stream);
    k_part<<<N_EDGES / EPB + 64, 256, 0, stream>>>(src, dst, bcnt, ebuf, W2, Bp);
    k_fill<<<NBKT, 256, 0, stream>>>(bcnt, ebuf, x, esrc64, cnt, dinv, xb, h1);

    // layer 1 fused: wide-row bf16 gather + LDS mm1 -> h1'
    k_agg1f<<<N_NODES / 32, 256, 0, stream>>>(cnt, esrc64, dinv, xb, W1, b1, h1);

    // layer 2 fused: gather -> private LDS slice -> MFMA (8 independent waves/block)
    k_l2<<<(N_NODES + 127) / 128, 512, 0, stream>>>(cnt, esrc64, dinv, h1, Bp, b2, Wl, snode);

    // pool + bias
    k_pool<<<N_GRAPHS, 256, 0, stream>>>(snode, batch, bl, out);
}

// Round 16
// 223.398 us; speedup vs baseline: 1.0487x; 1.0487x over previous
//
#include <hip/hip_runtime.h>
#include <hip/hip_bf16.h>

#define N_NODES 100000
#define N_EDGES 1600000
#define N_FEAT  16
#define HIDDEN  128
#define N_GRAPHS 512
#define CAP     64            // slots per node (mean deg 16, P(>63)~0)
#define NBKT    782           // ceil(100000/128) coarse buckets (dst>>7)
#define BN      128           // nodes per bucket
#define CAPB    2560          // edges per bucket cap (mean 2048, +11 sigma)
#define EPB     4000          // edges per k_part block (400 blocks)

typedef unsigned short ushort_t;
typedef short v8s __attribute__((ext_vector_type(8)));   // 8 bf16 (4 VGPRs)
typedef float v4f __attribute__((ext_vector_type(4)));   // MFMA accumulator

__device__ __forceinline__ ushort_t f2bf(float f) {
    __hip_bfloat16 b = __float2bfloat16(f);
    return *(ushort_t*)&b;
}
__device__ __forceinline__ float bf_lo(unsigned u) {
    union { unsigned i; float f; } c; c.i = u << 16; return c.f;
}
__device__ __forceinline__ float bf_hi(unsigned u) {
    union { unsigned i; float f; } c; c.i = u & 0xffff0000u; return c.f;
}

// ---------------- phase 1: coarse partition by dst>>7 (+ packB tail blocks) ----------------
// ebuf entry packed: v = src | (dst_local << 17)

__global__ __launch_bounds__(256) void k_part(const int* __restrict__ src,
                                              const int* __restrict__ dst,
                                              int* __restrict__ bcnt,
                                              int* __restrict__ ebuf,
                                              const float* __restrict__ W2,
                                              ushort_t* __restrict__ Bp) {
    int tid = threadIdx.x;

    if (blockIdx.x >= N_EDGES / EPB) {
        // packB: W2 -> bf16 MFMA B-fragment order
        int idx = (blockIdx.x - N_EDGES / EPB) * 256 + tid;   // 0..16383
        int j = idx & 7;
        int lane = (idx >> 3) & 63;
        int nt = (idx >> 9) & 7;
        int kt = idx >> 12;
        int k = kt * 32 + (lane >> 4) * 8 + j;
        int n = nt * 16 + (lane & 15);
        Bp[idx] = f2bf(W2[k * HIDDEN + n]);
        return;
    }

    __shared__ int h[NBKT];
    __shared__ int base[NBKT];
    __shared__ int r[NBKT];
    int e0 = blockIdx.x * EPB;

    for (int i = tid; i < NBKT; i += 256) { h[i] = 0; r[i] = 0; }
    __syncthreads();

    // EPB=4000: threads 0..159 handle 16 edges, the rest 15
    int nloc = (tid < EPB - 15 * 256) ? 16 : 15;
    int v[16], bb[16];
    #pragma unroll
    for (int k = 0; k < 16; ++k) {
        if (k < nloc) {
            int i = e0 + tid + k * 256;
            int s = src[i], d = dst[i];
            bb[k] = d >> 7;
            v[k] = s | ((d & 127) << 17);
            atomicAdd(&h[bb[k]], 1);
        }
    }
    __syncthreads();

    for (int i = tid; i < NBKT; i += 256)
        base[i] = atomicAdd(&bcnt[i], h[i]);
    __syncthreads();

    #pragma unroll
    for (int k = 0; k < 16; ++k) {
        if (k < nloc) {
            int b = bb[k];
            int pos = base[b] + atomicAdd(&r[b], 1);
            if (pos < CAPB) ebuf[b * CAPB + pos] = v[k];
        }
    }
}

// ---------------- phase 2: per-bucket LDS ranking + fused prescale ----------------

__global__ __launch_bounds__(256) void k_fill(const int* __restrict__ bcnt,
                                              const int* __restrict__ ebuf,
                                              const float* __restrict__ x,
                                              int* __restrict__ esrc64,
                                              int* __restrict__ cnt,
                                              float* __restrict__ dinv,
                                              ushort_t* __restrict__ xb,
                                              ushort_t* __restrict__ h1) {
    __shared__ int lcnt[BN];
    int tid = threadIdx.x;
    int b = blockIdx.x;
    int node0 = b << 7;

    if (tid < BN) lcnt[tid] = 0;
    __syncthreads();

    int nE = bcnt[b]; nE = nE > CAPB ? CAPB : nE;
    const int* eb = ebuf + b * CAPB;
    for (int i = tid; i < nE; i += 256) {
        int v = eb[i];
        int dl = v >> 17;
        int p = atomicAdd(&lcnt[dl], 1);
        if (p < CAP) esrc64[((node0 + dl) << 6) + p] = v & 0x1FFFF;
    }
    __syncthreads();

    if (tid < BN) {
        int node = node0 + tid;
        if (node < N_NODES) {
            int c = lcnt[tid];
            cnt[node] = c;
            dinv[node] = rsqrtf((float)c + 1.0f);
            int cc = c > CAP ? CAP : c;
            int pad = (cc + 7) & ~7;
            for (int p = cc; p < pad; ++p)
                esrc64[(node << 6) + p] = N_NODES;   // sentinel -> zero row
        }
    }

    for (int i = tid; i < BN * N_FEAT; i += 256) {
        int nl = i >> 4;
        int node = node0 + nl;
        if (node < N_NODES) {
            float di = rsqrtf((float)lcnt[nl] + 1.0f);
            xb[node * N_FEAT + (i & 15)] = f2bf(x[node * N_FEAT + (i & 15)] * di);
        }
    }

    if (b == 0) {
        if (tid < N_FEAT) xb[N_NODES * N_FEAT + tid] = 0;                 // xb sentinel row
        if (tid < HIDDEN) h1[(size_t)N_NODES * HIDDEN + tid] = 0;         // h1 sentinel row
    }
}

// ---------------- fused layer-1: wide-row gather (unroll 8) + LDS mm1 -> h1' ----------------

__global__ __launch_bounds__(256) void k_agg1f(const int* __restrict__ cnt,
                                               const int* __restrict__ esrc64,
                                               const float* __restrict__ dinv,
                                               const ushort_t* __restrict__ xb,
                                               const float* __restrict__ W1,
                                               const float* __restrict__ b1,
                                               ushort_t* __restrict__ h1) {
    __shared__ float sw[N_FEAT * HIDDEN];   // 8 KB
    __shared__ float sx[32][20];            // 16 feats padded to 20
    __shared__ float sdd[32];
    int tid = threadIdx.x;
    for (int i = tid; i < N_FEAT * HIDDEN; i += 256) sw[i] = W1[i];

    int wv = tid >> 6;
    int sub = (tid >> 3) & 7;    // node within wave
    int l8 = tid & 7;            // uint (2 feats) within row
    int nl = wv * 8 + sub;       // node local 0..31
    int node = blockIdx.x * 32 + nl;
    const unsigned* xr = (const unsigned*)xb;   // row = 8 uints

    int deg = cnt[node]; deg = deg > CAP ? CAP : deg;
    int deg8 = (deg + 7) & ~7;
    int base = node << 6;
    float dd = dinv[node];

    float a0 = 0.0f, a1 = 0.0f;
    for (int j = 0; j < deg8; j += 8) {
        int4 ia = *(const int4*)(esrc64 + base + j);
        int4 ib = *(const int4*)(esrc64 + base + j + 4);
        unsigned u0 = xr[(unsigned)ia.x * 8 + l8];
        unsigned u1 = xr[(unsigned)ia.y * 8 + l8];
        unsigned u2 = xr[(unsigned)ia.z * 8 + l8];
        unsigned u3 = xr[(unsigned)ia.w * 8 + l8];
        unsigned u4 = xr[(unsigned)ib.x * 8 + l8];
        unsigned u5 = xr[(unsigned)ib.y * 8 + l8];
        unsigned u6 = xr[(unsigned)ib.z * 8 + l8];
        unsigned u7 = xr[(unsigned)ib.w * 8 + l8];
        a0 += bf_lo(u0) + bf_lo(u1) + bf_lo(u2) + bf_lo(u3)
            + bf_lo(u4) + bf_lo(u5) + bf_lo(u6) + bf_lo(u7);
        a1 += bf_hi(u0) + bf_hi(u1) + bf_hi(u2) + bf_hi(u3)
            + bf_hi(u4) + bf_hi(u5) + bf_hi(u6) + bf_hi(u7);
    }
    unsigned su = xr[(unsigned)node * 8 + l8];
    a0 = (a0 + bf_lo(su)) * dd;
    a1 = (a1 + bf_hi(su)) * dd;

    sx[nl][2 * l8] = a0;
    sx[nl][2 * l8 + 1] = a1;
    if (l8 == 0) sdd[nl] = dd;
    __syncthreads();

    int f = tid & 127, half = tid >> 7;
    float bias = b1[f];
    float acc[16];
    #pragma unroll
    for (int n = 0; n < 16; ++n) acc[n] = bias;
    #pragma unroll
    for (int k4 = 0; k4 < 4; ++k4) {
        float w0 = sw[(k4 * 4 + 0) * HIDDEN + f];
        float w1 = sw[(k4 * 4 + 1) * HIDDEN + f];
        float w2 = sw[(k4 * 4 + 2) * HIDDEN + f];
        float w3 = sw[(k4 * 4 + 3) * HIDDEN + f];
        #pragma unroll
        for (int n = 0; n < 16; ++n) {
            float4 xv = *(const float4*)(&sx[half * 16 + n][k4 * 4]);
            acc[n] += xv.x * w0 + xv.y * w1 + xv.z * w2 + xv.w * w3;
        }
    }
    int n0 = blockIdx.x * 32 + half * 16;
    #pragma unroll
    for (int n = 0; n < 16; ++n)
        h1[(size_t)(n0 + n) * HIDDEN + f] =
            f2bf(sdd[half * 16 + n] * fmaxf(acc[n], 0.0f));
}

// ---------------- fused layer-2: gather -> LDS -> MFMA mm2 + head ----------------
// Block = 256 threads = 4 INDEPENDENT waves = 64 nodes; 16.9 KB LDS; NO barrier
// (each wave writes+reads only its own 16-row LDS slice). __launch_bounds__(256)
// leaves the allocator free (~52 VGPR) for the 8-deep gather pipeline.

__global__ __launch_bounds__(256) void k_l2(const int* __restrict__ cnt,
                                            const int* __restrict__ esrc64,
                                            const float* __restrict__ dinv,
                                            const ushort_t* __restrict__ h1,
                                            const ushort_t* __restrict__ Bp,
                                            const float* __restrict__ b2,
                                            const float* __restrict__ Wl,
                                            float* __restrict__ snode) {
    __shared__ ushort_t sA[64 * 132];   // 16.9 KB
    int tid = threadIdx.x;
    int wv = tid >> 6, lane = tid & 63;
    int half = lane >> 5, l32 = lane & 31;
    int node0 = blockIdx.x * 64;
    const uint2* h = (const uint2*)h1;

    for (int p = 0; p < 8; ++p) {
        int nl = wv * 16 + p * 2 + half;
        int nodeIdx = node0 + nl;
        int node = nodeIdx < N_NODES ? nodeIdx : 0;   // clamp (last block only)
        int deg = cnt[node]; deg = deg > CAP ? CAP : deg;
        int deg8 = (deg + 7) & ~7;
        int base = node << 6;
        float dd = dinv[node];
        uint2 sv = h[node * 32 + l32];
        float a0 = bf_lo(sv.x), a1 = bf_hi(sv.x), a2 = bf_lo(sv.y), a3 = bf_hi(sv.y);

        for (int j = 0; j < deg8; j += 8) {
            int4 ia = *(const int4*)(esrc64 + base + j);
            int4 ib = *(const int4*)(esrc64 + base + j + 4);
            uint2 v0 = h[(unsigned)ia.x * 32 + l32];
            uint2 v1 = h[(unsigned)ia.y * 32 + l32];
            uint2 v2 = h[(unsigned)ia.z * 32 + l32];
            uint2 v3 = h[(unsigned)ia.w * 32 + l32];
            uint2 v4 = h[(unsigned)ib.x * 32 + l32];
            uint2 v5 = h[(unsigned)ib.y * 32 + l32];
            uint2 v6 = h[(unsigned)ib.z * 32 + l32];
            uint2 v7 = h[(unsigned)ib.w * 32 + l32];
            a0 += bf_lo(v0.x) + bf_lo(v1.x) + bf_lo(v2.x) + bf_lo(v3.x)
                + bf_lo(v4.x) + bf_lo(v5.x) + bf_lo(v6.x) + bf_lo(v7.x);
            a1 += bf_hi(v0.x) + bf_hi(v1.x) + bf_hi(v2.x) + bf_hi(v3.x)
                + bf_hi(v4.x) + bf_hi(v5.x) + bf_hi(v6.x) + bf_hi(v7.x);
            a2 += bf_lo(v0.y) + bf_lo(v1.y) + bf_lo(v2.y) + bf_lo(v3.y)
                + bf_lo(v4.y) + bf_lo(v5.y) + bf_lo(v6.y) + bf_lo(v7.y);
            a3 += bf_hi(v0.y) + bf_hi(v1.y) + bf_hi(v2.y) + bf_hi(v3.y)
                + bf_hi(v4.y) + bf_hi(v5.y) + bf_hi(v6.y) + bf_hi(v7.y);
        }
        ushort4 r;
        r.x = f2bf(a0 * dd); r.y = f2bf(a1 * dd);
        r.z = f2bf(a2 * dd); r.w = f2bf(a3 * dd);
        *(ushort4*)(&sA[nl * 132 + l32 * 4]) = r;
    }
    // no __syncthreads: wave reads only its own LDS rows (lgkmcnt handled by compiler)

    // phase 2: MFMA. wave wv handles rows wv*16..+15 (the ones it wrote).
    int m = lane & 15, quad = lane >> 4;
    const ushort_t* arow = &sA[(wv * 16 + m) * 132];

    v4f acc[8];
    #pragma unroll
    for (int nt = 0; nt < 8; ++nt) acc[nt] = (v4f){0.f, 0.f, 0.f, 0.f};

    #pragma unroll
    for (int kt = 0; kt < 4; ++kt) {
        union { v8s v; ushort4 q[2]; } au;
        au.q[0] = *(const ushort4*)(arow + kt * 32 + quad * 8);
        au.q[1] = *(const ushort4*)(arow + kt * 32 + quad * 8 + 4);
        #pragma unroll
        for (int nt = 0; nt < 8; ++nt) {
            v8s b = *(const v8s*)(Bp + ((kt * 8 + nt) * 64 + lane) * 8);
            acc[nt] = __builtin_amdgcn_mfma_f32_16x16x32_bf16(au.v, b, acc[nt], 0, 0, 0);
        }
    }

    float part[4] = {0, 0, 0, 0};
    #pragma unroll
    for (int nt = 0; nt < 8; ++nt) {
        float bb = b2[nt * 16 + m];
        float wl = Wl[nt * 16 + m];
        #pragma unroll
        for (int reg = 0; reg < 4; ++reg)
            part[reg] += fmaxf(acc[nt][reg] + bb, 0.0f) * wl;
    }
    int node0b = node0 + wv * 16;
    #pragma unroll
    for (int reg = 0; reg < 4; ++reg) {
        float p = part[reg];
        p += __shfl_xor(p, 1, 64);
        p += __shfl_xor(p, 2, 64);
        p += __shfl_xor(p, 4, 64);
        p += __shfl_xor(p, 8, 64);
        int node = node0b + quad * 4 + reg;
        if (m == 0 && node < N_NODES) snode[node] = p;
    }
}

// ---------------- pooling: out[g] = mean(snode over graph g) + bl ----------------

__global__ __launch_bounds__(256) void k_pool(const float* __restrict__ snode,
                                              const int* __restrict__ batch,
                                              const float* __restrict__ bl,
                                              float* __restrict__ out) {
    int g = blockIdx.x;
    int tid = threadIdx.x;
    __shared__ float sred[4];

    int lo = 0, hi = N_NODES;
    while (lo < hi) { int mid = (lo + hi) >> 1; if (batch[mid] < g) lo = mid + 1; else hi = mid; }
    int start = lo;
    hi = N_NODES;
    while (lo < hi) { int mid = (lo + hi) >> 1; if (batch[mid] < g + 1) lo = mid + 1; else hi = mid; }
    int end = lo;

    float acc = 0.0f;
    for (int n = start + tid; n < end; n += 256) acc += snode[n];

    #pragma unroll
    for (int off = 32; off; off >>= 1) acc += __shfl_down(acc, off, 64);
    int wave = tid >> 6, lane = tid & 63;
    if (lane == 0) sred[wave] = acc;
    __syncthreads();
    if (tid == 0) {
        float s = sred[0] + sred[1] + sred[2] + sred[3];
        float cnt = (float)(end - start);
        out[g] = s / fmaxf(cnt, 1.0f) + bl[0];
    }
}

// ---------------- launch ----------------

extern "C" void kernel_launch(void* const* d_in, const int* in_sizes, int n_in,
                              void* d_out, int out_size, void* d_ws, size_t ws_size,
                              hipStream_t stream) {
    const float* x    = (const float*)d_in[0];
    const int*   src  = (const int*)d_in[1];
    const int*   dst  = src + N_EDGES;
    const int*   batch= (const int*)d_in[2];
    const float* W1   = (const float*)d_in[3];
    const float* b1   = (const float*)d_in[4];
    const float* W2   = (const float*)d_in[5];
    const float* b2   = (const float*)d_in[6];
    const float* Wl   = (const float*)d_in[7];
    const float* bl   = (const float*)d_in[8];
    float* out = (float*)d_out;

    // byte-offset workspace layout, 256 B aligned chunks
    char* w = (char*)d_ws;
    size_t off = 0;
    auto alloc = [&](size_t bytes) { char* p = w + off; off = (off + bytes + 255) & ~(size_t)255; return p; };

    ushort_t* h1   = (ushort_t*)alloc((size_t)(N_NODES + 1) * HIDDEN * 2);   // 25.6 MB (+sentinel)
    int*   ebuf    = (int*)alloc((size_t)NBKT * CAPB * 4);                    // 8.0 MB
    ushort_t* xb   = (ushort_t*)alloc((size_t)(N_NODES + 1) * N_FEAT * 2);   // 3.2 MB (+sentinel)
    float* dinv    = (float*)alloc(N_NODES * 4);
    float* snode   = (float*)alloc(N_NODES * 4);
    int*   cnt     = (int*)alloc(N_NODES * 4);
    int*   esrc64  = (int*)alloc((size_t)N_NODES * CAP * 4);                  // 25.6 MB
    ushort_t* Bp   = (ushort_t*)alloc(16384 * 2);                             // 32 KB
    int*   bcnt    = (int*)alloc(NBKT * 4);

    // build: memset bcnt, partition (+packB tail), per-bucket rank (+prescale+sentinels)
    hipMemsetAsync(bcnt, 0, NBKT * sizeof(int), stream);
    k_part<<<N_EDGES / EPB + 64, 256, 0, stream>>>(src, dst, bcnt, ebuf, W2, Bp);
    k_fill<<<NBKT, 256, 0, stream>>>(bcnt, ebuf, x, esrc64, cnt, dinv, xb, h1);

    // layer 1 fused: wide-row bf16 gather + LDS mm1 -> h1'
    k_agg1f<<<N_NODES / 32, 256, 0, stream>>>(cnt, esrc64, dinv, xb, W1, b1, h1);

    // layer 2 fused: gather -> private LDS slice -> MFMA (4 independent waves/block)
    k_l2<<<(N_NODES + 63) / 64, 256, 0, stream>>>(cnt, esrc64, dinv, h1, Bp, b2, Wl, snode);

    // pool + bias
    k_pool<<<N_GRAPHS, 256, 0, stream>>>(snode, batch, bl, out);
}